// Round 1
// baseline (135.341 us; speedup 1.0000x reference)
//
#include <hip/hip_runtime.h>
#include <hip/hip_bf16.h>
#include <stdint.h>

#define N    8192
#define D    256
#define NCLS 100

static constexpr float TEMP    = 0.5f;
static constexpr float SCALE_F = 1.69864360f;  // sqrt(log2e/TEMP)
static constexpr float LN2     = 0.69314718055994531f;

typedef float f32x4 __attribute__((ext_vector_type(4)));

__device__ __forceinline__ unsigned short f2bf(float f) {
  union { float f; unsigned int u; } x; x.f = f;
  unsigned int r = x.u + 0x7fffu + ((x.u >> 16) & 1u);
  return (unsigned short)(r >> 16);
}
__device__ __forceinline__ float bf2f(unsigned short b) {
  union { unsigned int u; float f; } x; x.u = ((unsigned int)b) << 16;
  return x.f;
}
__device__ __forceinline__ void gld16(const void* g, void* l) {
  __builtin_amdgcn_global_load_lds(
      (const __attribute__((address_space(1))) unsigned int*)g,
      (__attribute__((address_space(3))) unsigned int*)l, 16, 0, 0);
}

// fp8 fragment-major layout:
//   addr(r, k) = (r>>4)*4096 + (k>>3)*128 + (r&15)*8 + (k&7)
// -> GEMM LDS reads are lane-linear 128B segments (0 bank conflicts);
// -> staging is a flat contiguous copy; K-quarters of a panel are contiguous.

// ---- Kernel A: row-normalize; bf16 row-major copy (class sums) + fp8 e4m3
// fragment-major copy (GEMM); also zeroes rowsum (folds the memset).
__global__ __launch_bounds__(256) void normalize_kernel(
    const float* __restrict__ emb, const long long* __restrict__ label,
    unsigned short* __restrict__ abf, unsigned char* __restrict__ a8,
    float* __restrict__ rowsum, int* __restrict__ cnt,
    int* __restrict__ list) {
  const int row  = blockIdx.x * 4 + (threadIdx.x >> 6);
  const int lane = threadIdx.x & 63;
  const float4 v = ((const float4*)(emb + (size_t)row * D))[lane];
  float ss = v.x * v.x + v.y * v.y + v.z * v.z + v.w * v.w;
#pragma unroll
  for (int off = 1; off < 64; off <<= 1) ss += __shfl_xor(ss, off);
  const float s = rsqrtf(ss) * SCALE_F;
  const float x = v.x * s, y = v.y * s, z = v.z * s, wv = v.w * s;

  ushort4 o;
  o.x = f2bf(x); o.y = f2bf(y); o.z = f2bf(z); o.w = f2bf(wv);
  ((ushort4*)(abf + (size_t)row * D))[lane] = o;

  int p = __builtin_amdgcn_cvt_pk_fp8_f32(x, y, 0, false);
  p = __builtin_amdgcn_cvt_pk_fp8_f32(z, wv, p, true);
  // k = lane*4 .. +3 -> octet = lane>>1, 4B half = lane&1
  *(int*)(a8 + (size_t)(row >> 4) * 4096 + (lane >> 1) * 128 +
          (row & 15) * 8 + (lane & 1) * 4) = p;

  if (lane == 0) {
    rowsum[row] = 0.f;
    const int c = (int)label[row];
    const int slot = atomicAdd(cnt + c, 1);
    list[c * 256 + slot] = row;
  }
}

// ---- Kernel B: symmetric (upper-triangle only). exp(sim) is symmetric
// bit-exactly (same fp8 products, same K accumulation order), so each
// strictly-upper element feeds rowsum[i] (row reduce) AND rowsum[j]
// (col reduce + atomic). Diagonal excluded here (finalize no longer
// subtracts E2). Lower-triangle tiles exit immediately; straddle tiles
// skip whole 128-col sub-tiles below the diagonal and mask the diagonal
// sub-tile with i<j.
// A-tile resident full-K in LDS; B staged in QUARTER-K double buffers
// (2x8 KB) so LDS = 48 KB -> 3 blocks/CU -> all 544 live blocks
// co-resident (no scheduling tail from 544 > 512).
#define TM 128
#define TN 128
#define JT 4

__global__ __launch_bounds__(256, 3) void simexp_rowsum_kernel(
    const unsigned char* __restrict__ A, float* __restrict__ rowsum) {
  __shared__ __align__(16) unsigned char sa[TM * 256];    // 32 KB, full K
  __shared__ __align__(16) unsigned char sb[2][TN * 64];  // 2 x 8 KB quarter-K
  const int tid  = threadIdx.x;
  const int w    = tid >> 6;
  const int lane = tid & 63;
  const int quad = lane >> 4;
  const int l15  = lane & 15;
  const int row0 = blockIdx.y * TM;
  const int jc0  = blockIdx.x * (TN * JT);
  if (row0 >= jc0 + TN * JT) return;  // strictly below diagonal: symmetric twin
  const int sdiag = (row0 >= jc0) ? ((row0 - jc0) >> 7) : -1;  // diag sub-tile
  const int jt0   = (sdiag >= 0) ? sdiag : 0;  // skip sub-tiles fully below
  const int pr0 = row0 >> 4;       // first 16-row panel of A-tile
  const int pam = (w & 1) * 4;     // wave's A panel base (local)
  const int pbn = (w >> 1) * 4;    // wave's B panel base (local)
  const int wm  = (w & 1) * 64;
  const int jn0 = (w >> 1) * 64;

  // Stage full A-tile: 32 segs of 1024 B; wave w stages segs w*8..w*8+7.
#pragma unroll
  for (int p = 0; p < 8; ++p) {
    const int seg = w * 8 + p;  // wave-uniform
    gld16(A + (size_t)(pr0 + (seg >> 2)) * 4096 + (seg & 3) * 1024 + lane * 16,
          sa + seg * 1024);
  }
  // Stage B(jt0, kq=0) into buffer 0: 8 segs of 1024 B.
  {
    const int pj0 = (jc0 + jt0 * TN) >> 4;
#pragma unroll
    for (int p = 0; p < 2; ++p) {
      const int seg = w * 2 + p;
      gld16(A + (size_t)(pj0 + seg) * 4096 + lane * 16, sb[0] + seg * 1024);
    }
  }
  __syncthreads();

  float rowpart[4][4];
#pragma unroll
  for (int mt = 0; mt < 4; ++mt)
#pragma unroll
    for (int e = 0; e < 4; ++e) rowpart[mt][e] = 0.f;

  int buf = 0;
  for (int jt = jt0; jt < JT; ++jt) {
    f32x4 acc[4][4];
#pragma unroll
    for (int mt = 0; mt < 4; ++mt)
#pragma unroll
      for (int nt = 0; nt < 4; ++nt) acc[mt][nt] = (f32x4){0.f, 0.f, 0.f, 0.f};

#pragma unroll
    for (int kq = 0; kq < 4; ++kq) {
      // Prefetch the next quarter-K B chunk into the other buffer.
      if (!(jt == JT - 1 && kq == 3)) {
        const int njt = (kq == 3) ? jt + 1 : jt;
        const int nkq = (kq + 1) & 3;
        const int pj0 = (jc0 + njt * TN) >> 4;
#pragma unroll
        for (int p = 0; p < 2; ++p) {
          const int seg = w * 2 + p;
          gld16(A + (size_t)(pj0 + seg) * 4096 + nkq * 1024 + lane * 16,
                sb[buf ^ 1] + seg * 1024);
        }
      }
      // Compute quarter kq from sb[buf] against resident A.
#pragma unroll
      for (int kkl = 0; kkl < 2; ++kkl) {
        const int fo = (kkl * 4 + quad) * 128 + l15 * 8;  // lane-linear
        long af[4], bf[4];
#pragma unroll
        for (int mt = 0; mt < 4; ++mt)
          af[mt] = *(const long*)(sa + (pam + mt) * 4096 + kq * 1024 + fo);
#pragma unroll
        for (int nt = 0; nt < 4; ++nt)
          bf[nt] = *(const long*)(sb[buf] + (pbn + nt) * 1024 + fo);
#pragma unroll
        for (int mt = 0; mt < 4; ++mt)
#pragma unroll
          for (int nt = 0; nt < 4; ++nt)
            acc[mt][nt] = __builtin_amdgcn_mfma_f32_16x16x32_fp8_fp8(
                af[mt], bf[nt], acc[mt][nt], 0, 0, 0);
      }
      __syncthreads();
      buf ^= 1;
    }

    // Epilogue for this 128-col sub-tile: exp2, diagonal mask, row partials
    // (accumulated across jt) and column sums (reduced + atomic now, since
    // columns change per jt).
    const bool diag = (jt == sdiag);
    float colpart[4] = {0.f, 0.f, 0.f, 0.f};
#pragma unroll
    for (int mt = 0; mt < 4; ++mt)
#pragma unroll
      for (int nt = 0; nt < 4; ++nt)
#pragma unroll
        for (int e = 0; e < 4; ++e) {
          float v = __builtin_amdgcn_exp2f(acc[mt][nt][e]);
          if (diag) {
            const int iloc = wm + mt * 16 + quad * 4 + e;
            const int jloc = jn0 + nt * 16 + l15;
            v = (iloc < jloc) ? v : 0.f;
          }
          rowpart[mt][e] += v;
          colpart[nt] += v;
        }
    // Column reduce over rows: sum across quad (lane bits 4,5), then one
    // atomic per column per wave.
#pragma unroll
    for (int nt = 0; nt < 4; ++nt) {
      float v = colpart[nt];
      v += __shfl_xor(v, 16);
      v += __shfl_xor(v, 32);
      if (quad == 0)
        atomicAdd(&rowsum[jc0 + jt * TN + jn0 + nt * 16 + l15], v);
    }
  }

  // Row reduce: C layout col = l15, row-in-16 = quad*4 + e. Reduce over 16
  // cols, one atomic per row per block.
#pragma unroll
  for (int mt = 0; mt < 4; ++mt)
#pragma unroll
    for (int e = 0; e < 4; ++e) {
      float v = rowpart[mt][e];
      v += __shfl_xor(v, 1);
      v += __shfl_xor(v, 2);
      v += __shfl_xor(v, 4);
      v += __shfl_xor(v, 8);
      if (l15 == 0)
        atomicAdd(&rowsum[row0 + wm + mt * 16 + quad * 4 + e], v);
    }
}

__global__ __launch_bounds__(256) void finalize_kernel(
    const unsigned short* __restrict__ abf, const float* __restrict__ rowsum,
    const long long* __restrict__ label, const int* __restrict__ cnt,
    const int* __restrict__ list, float* __restrict__ out) {
  __shared__ float red[4];
  __shared__ int rows_l[256];
  const int tid  = threadIdx.x;
  const int w    = tid >> 6;
  const int lane = tid & 63;

  if (blockIdx.x < NCLS) {
    const int c = blockIdx.x;
    const int m = cnt[c];
    if (m <= 1) return;
    if (tid < m) rows_l[tid] = list[c * 256 + tid];
    __syncthreads();
    float acc = 0.f;
    for (int s = 0; s < m; ++s)
      acc += bf2f(abf[(size_t)rows_l[s] * D + tid]);
    float v = acc * acc;
#pragma unroll
    for (int off = 1; off < 64; off <<= 1) v += __shfl_xor(v, off);
    if (lane == 0) red[w] = v;
    __syncthreads();
    if (tid == 0) {
      const float ssq = red[0] + red[1] + red[2] + red[3];
      const float term = (ssq * LN2 - 2.0f * (float)m) / (float)(m - 1);
      atomicAdd(out, -term);
    }
  } else {
    // rowsum now already excludes the diagonal (symmetric kernel computes
    // strict upper triangle only), so no E2 subtraction.
    const int i = (blockIdx.x - NCLS) * 256 + tid;
    const int c = (int)label[i];
    float v = 0.f;
    if (cnt[c] > 1)
      v = __builtin_amdgcn_logf(rowsum[i]) * LN2;
#pragma unroll
    for (int off = 1; off < 64; off <<= 1) v += __shfl_xor(v, off);
    if (lane == 0) red[w] = v;
    __syncthreads();
    if (tid == 0)
      atomicAdd(out, red[0] + red[1] + red[2] + red[3]);
  }
}

extern "C" void kernel_launch(void* const* d_in, const int* in_sizes, int n_in,
                              void* d_out, int out_size, void* d_ws,
                              size_t ws_size, hipStream_t stream) {
  const float* emb = (const float*)d_in[0];
  const long long* label = (const long long*)d_in[1];
  float* out = (float*)d_out;

  char* ws = (char*)d_ws;
  unsigned short* abf = (unsigned short*)ws;            // 4 MB bf16 row-major
  unsigned char* a8 = (unsigned char*)(ws + (size_t)N * D * 2);  // 2 MB fp8
  float* rowsum = (float*)(ws + (size_t)N * D * 3);     // N floats
  int* cnt = (int*)(rowsum + N);                        // 128 ints
  int* list = cnt + 128;                                // NCLS*256 ints

  hipMemsetAsync(cnt, 0, 128 * 4, stream);
  hipMemsetAsync(out, 0, sizeof(float), stream);

  normalize_kernel<<<N / 4, 256, 0, stream>>>(emb, label, abf, a8, rowsum,
                                              cnt, list);

  dim3 gridB(N / (TN * JT), N / TM);  // (16, 64); 544 blocks do work
  simexp_rowsum_kernel<<<gridB, 256, 0, stream>>>(a8, rowsum);

  finalize_kernel<<<NCLS + N / 256, 256, 0, stream>>>(abf, rowsum, label, cnt,
                                                      list, out);
}

// Round 2
// 129.903 us; speedup vs baseline: 1.0419x; 1.0419x over previous
//
#include <hip/hip_runtime.h>
#include <hip/hip_bf16.h>
#include <stdint.h>

#define N    8192
#define D    256
#define NCLS 100

static constexpr float TEMP    = 0.5f;
static constexpr float SCALE_F = 1.69864360f;  // sqrt(log2e/TEMP)
static constexpr float LN2     = 0.69314718055994531f;

typedef float f32x4 __attribute__((ext_vector_type(4)));

__device__ __forceinline__ unsigned short f2bf(float f) {
  union { float f; unsigned int u; } x; x.f = f;
  unsigned int r = x.u + 0x7fffu + ((x.u >> 16) & 1u);
  return (unsigned short)(r >> 16);
}
__device__ __forceinline__ float bf2f(unsigned short b) {
  union { unsigned int u; float f; } x; x.u = ((unsigned int)b) << 16;
  return x.f;
}
__device__ __forceinline__ void gld16(const void* g, void* l) {
  __builtin_amdgcn_global_load_lds(
      (const __attribute__((address_space(1))) unsigned int*)g,
      (__attribute__((address_space(3))) unsigned int*)l, 16, 0, 0);
}

// fp8 fragment-major layout:
//   addr(r, k) = (r>>4)*4096 + (k>>3)*128 + (r&15)*8 + (k&7)
// -> fragment reads (LDS or global) are lane-linear 512B segments:
//    perfectly coalesced global_load_dwordx2 / conflict-free ds_read_b64.

// ---- Kernel A: row-normalize; bf16 row-major copy (class sums) + fp8 e4m3
// fragment-major copy (GEMM); also zeroes rowsum (folds the memset).
__global__ __launch_bounds__(256) void normalize_kernel(
    const float* __restrict__ emb, const long long* __restrict__ label,
    unsigned short* __restrict__ abf, unsigned char* __restrict__ a8,
    float* __restrict__ rowsum, int* __restrict__ cnt,
    int* __restrict__ list) {
  const int row  = blockIdx.x * 4 + (threadIdx.x >> 6);
  const int lane = threadIdx.x & 63;
  const float4 v = ((const float4*)(emb + (size_t)row * D))[lane];
  float ss = v.x * v.x + v.y * v.y + v.z * v.z + v.w * v.w;
#pragma unroll
  for (int off = 1; off < 64; off <<= 1) ss += __shfl_xor(ss, off);
  const float s = rsqrtf(ss) * SCALE_F;
  const float x = v.x * s, y = v.y * s, z = v.z * s, wv = v.w * s;

  ushort4 o;
  o.x = f2bf(x); o.y = f2bf(y); o.z = f2bf(z); o.w = f2bf(wv);
  ((ushort4*)(abf + (size_t)row * D))[lane] = o;

  int p = __builtin_amdgcn_cvt_pk_fp8_f32(x, y, 0, false);
  p = __builtin_amdgcn_cvt_pk_fp8_f32(z, wv, p, true);
  // k = lane*4 .. +3 -> octet = lane>>1, 4B half = lane&1
  *(int*)(a8 + (size_t)(row >> 4) * 4096 + (lane >> 1) * 128 +
          (row & 15) * 8 + (lane & 1) * 4) = p;

  if (lane == 0) {
    rowsum[row] = 0.f;
    const int c = (int)label[row];
    const int slot = atomicAdd(cnt + c, 1);
    list[c * 256 + slot] = row;
  }
}

// ---- Kernel B: symmetric (strict upper triangle). exp(sim) is bit-exactly
// symmetric (same fp8 products, same K accumulation order), so each upper
// element feeds rowsum[i] (row reduce) AND rowsum[j] (col reduce + atomic).
//
// R2 restructure (latency-bound fix): A-tile resident in LDS (staged once,
// ONE barrier total); B fragments read DIRECTLY global->register. The 2 MB
// fp8 matrix is L2-resident, so B needs no LDS staging, and removing the
// per-phase __syncthreads removes the vmcnt(0) drains that were stalling
// every phase (R1: MfmaUtil 13%, all pipes idle). The fully unrolled K-loop
// lets the compiler hoist B loads over MFMA clusters (~310 cyc/wave per
// 16-MFMA group covers ~200 cyc L2 latency).
// Grid compacted to the 544 live blocks via triangular decode.
#define TM 128
#define TN 128
#define JT 4

__global__ __launch_bounds__(256, 3) void simexp_rowsum_kernel(
    const unsigned char* __restrict__ A, float* __restrict__ rowsum) {
  __shared__ __align__(16) unsigned char sa[TM * 256];  // 32 KB, full-K A tile
  const int tid  = threadIdx.x;
  const int w    = tid >> 6;
  const int lane = tid & 63;
  const int quad = lane >> 4;
  const int l15  = lane & 15;

  // Triangular decode: block b -> (x, y), live iff y*TM < x*512 + 512.
  // count(x) = 4x+4, cum(x) = 2x^2+2x.
  const int b = blockIdx.x;
  int x = (int)((-1.0f + sqrtf(1.0f + 2.0f * (float)b)) * 0.5f);
  while (2 * (x + 1) * (x + 1) + 2 * (x + 1) <= b) ++x;
  while (2 * x * x + 2 * x > b) --x;
  const int y = b - (2 * x * x + 2 * x);

  const int row0 = y * TM;
  const int jc0  = x * (TN * JT);
  const int sdiag = (y >= 4 * x) ? (y - 4 * x) : -1;  // diagonal sub-tile
  const int jt0   = (sdiag >= 0) ? sdiag : 0;
  const int pr0 = row0 >> 4;     // first 16-row panel of A-tile
  const int pam = (w & 1) * 4;   // wave's A panel base (local)
  const int pbn = (w >> 1) * 4;  // wave's B panel base (global panel offset)
  const int wm  = (w & 1) * 64;
  const int jn0 = (w >> 1) * 64;

  // Stage full A-tile: 32 segs of 1024 B; wave w stages segs w*8..w*8+7.
#pragma unroll
  for (int p = 0; p < 8; ++p) {
    const int seg = w * 8 + p;  // wave-uniform
    gld16(A + (size_t)(pr0 + (seg >> 2)) * 4096 + (seg & 3) * 1024 + lane * 16,
          sa + seg * 1024);
  }
  __syncthreads();  // the only barrier in this kernel

  float rowpart[4][4];
#pragma unroll
  for (int mt = 0; mt < 4; ++mt)
#pragma unroll
    for (int e = 0; e < 4; ++e) rowpart[mt][e] = 0.f;

  for (int jt = jt0; jt < JT; ++jt) {
    // B panel base for this wave's 4 column panels of this sub-tile.
    const unsigned char* Bp =
        A + (size_t)(((jc0 + jt * TN) >> 4) + pbn) * 4096;

    f32x4 acc[4][4];
#pragma unroll
    for (int mt = 0; mt < 4; ++mt)
#pragma unroll
      for (int nt = 0; nt < 4; ++nt) acc[mt][nt] = (f32x4){0.f, 0.f, 0.f, 0.f};

#pragma unroll
    for (int kq = 0; kq < 4; ++kq) {
#pragma unroll
      for (int kkl = 0; kkl < 2; ++kkl) {
        const int fo = (kkl * 4 + quad) * 128 + l15 * 8;  // lane-linear
        long af[4], bf[4];
#pragma unroll
        for (int nt = 0; nt < 4; ++nt)  // global -> reg (coalesced 512B/seg)
          bf[nt] = *(const long*)(Bp + nt * 4096 + kq * 1024 + fo);
#pragma unroll
        for (int mt = 0; mt < 4; ++mt)  // LDS -> reg (conflict-free)
          af[mt] = *(const long*)(sa + (pam + mt) * 4096 + kq * 1024 + fo);
#pragma unroll
        for (int mt = 0; mt < 4; ++mt)
#pragma unroll
          for (int nt = 0; nt < 4; ++nt)
            acc[mt][nt] = __builtin_amdgcn_mfma_f32_16x16x32_fp8_fp8(
                af[mt], bf[nt], acc[mt][nt], 0, 0, 0);
      }
    }

    // Epilogue for this 128-col sub-tile: exp2, diagonal mask, row partials
    // (accumulated across jt) and column sums (reduced + atomic per jt).
    const bool diag = (jt == sdiag);
    float colpart[4] = {0.f, 0.f, 0.f, 0.f};
#pragma unroll
    for (int mt = 0; mt < 4; ++mt)
#pragma unroll
      for (int nt = 0; nt < 4; ++nt)
#pragma unroll
        for (int e = 0; e < 4; ++e) {
          float v = __builtin_amdgcn_exp2f(acc[mt][nt][e]);
          if (diag) {
            const int iloc = wm + mt * 16 + quad * 4 + e;
            const int jloc = jn0 + nt * 16 + l15;
            v = (iloc < jloc) ? v : 0.f;
          }
          rowpart[mt][e] += v;
          colpart[nt] += v;
        }
    // Column reduce over rows: sum across quad (lane bits 4,5), then one
    // atomic per column per wave.
#pragma unroll
    for (int nt = 0; nt < 4; ++nt) {
      float v = colpart[nt];
      v += __shfl_xor(v, 16);
      v += __shfl_xor(v, 32);
      if (quad == 0)
        atomicAdd(&rowsum[jc0 + jt * TN + jn0 + nt * 16 + l15], v);
    }
  }

  // Row reduce: C layout col = l15, row-in-16 = quad*4 + e. Reduce over 16
  // cols, one atomic per row per block.
#pragma unroll
  for (int mt = 0; mt < 4; ++mt)
#pragma unroll
    for (int e = 0; e < 4; ++e) {
      float v = rowpart[mt][e];
      v += __shfl_xor(v, 1);
      v += __shfl_xor(v, 2);
      v += __shfl_xor(v, 4);
      v += __shfl_xor(v, 8);
      if (l15 == 0)
        atomicAdd(&rowsum[row0 + wm + mt * 16 + quad * 4 + e], v);
    }
}

__global__ __launch_bounds__(256) void finalize_kernel(
    const unsigned short* __restrict__ abf, const float* __restrict__ rowsum,
    const long long* __restrict__ label, const int* __restrict__ cnt,
    const int* __restrict__ list, float* __restrict__ out) {
  __shared__ float red[4];
  __shared__ int rows_l[256];
  const int tid  = threadIdx.x;
  const int w    = tid >> 6;
  const int lane = tid & 63;

  if (blockIdx.x < NCLS) {
    const int c = blockIdx.x;
    const int m = cnt[c];
    if (m <= 1) return;
    if (tid < m) rows_l[tid] = list[c * 256 + tid];
    __syncthreads();
    float acc = 0.f;
    for (int s = 0; s < m; ++s)
      acc += bf2f(abf[(size_t)rows_l[s] * D + tid]);
    float v = acc * acc;
#pragma unroll
    for (int off = 1; off < 64; off <<= 1) v += __shfl_xor(v, off);
    if (lane == 0) red[w] = v;
    __syncthreads();
    if (tid == 0) {
      const float ssq = red[0] + red[1] + red[2] + red[3];
      const float term = (ssq * LN2 - 2.0f * (float)m) / (float)(m - 1);
      atomicAdd(out, -term);
    }
  } else {
    // rowsum already excludes the diagonal (strict upper triangle only).
    const int i = (blockIdx.x - NCLS) * 256 + tid;
    const int c = (int)label[i];
    float v = 0.f;
    if (cnt[c] > 1)
      v = __builtin_amdgcn_logf(rowsum[i]) * LN2;
#pragma unroll
    for (int off = 1; off < 64; off <<= 1) v += __shfl_xor(v, off);
    if (lane == 0) red[w] = v;
    __syncthreads();
    if (tid == 0)
      atomicAdd(out, red[0] + red[1] + red[2] + red[3]);
  }
}

extern "C" void kernel_launch(void* const* d_in, const int* in_sizes, int n_in,
                              void* d_out, int out_size, void* d_ws,
                              size_t ws_size, hipStream_t stream) {
  const float* emb = (const float*)d_in[0];
  const long long* label = (const long long*)d_in[1];
  float* out = (float*)d_out;

  char* ws = (char*)d_ws;
  unsigned short* abf = (unsigned short*)ws;            // 4 MB bf16 row-major
  unsigned char* a8 = (unsigned char*)(ws + (size_t)N * D * 2);  // 2 MB fp8
  float* rowsum = (float*)(ws + (size_t)N * D * 3);     // N floats
  int* cnt = (int*)(rowsum + N);                        // 128 ints
  int* list = cnt + 128;                                // NCLS*256 ints

  hipMemsetAsync(cnt, 0, 128 * 4, stream);
  hipMemsetAsync(out, 0, sizeof(float), stream);

  normalize_kernel<<<N / 4, 256, 0, stream>>>(emb, label, abf, a8, rowsum,
                                              cnt, list);

  simexp_rowsum_kernel<<<544, 256, 0, stream>>>(a8, rowsum);

  finalize_kernel<<<NCLS + N / 256, 256, 0, stream>>>(abf, rowsum, label, cnt,
                                                      list, out);
}